// Round 13
// baseline (209.696 us; speedup 1.0000x reference)
//
#include <hip/hip_runtime.h>
#include <math.h>

#define NUM_AGENTS 256
#define HIDDEN 1024
#define RANK 32
#define NTOK 8192
#define TBATCH 8          // tokens per block = 4 waves x 2 tokens
#define MAXPER 128        // per-agent token cap
#define REGCAP 256        // descriptor slots per XCD region
#define ALPHA_MAX 5.0f
#define LN_EPS 1e-5f

// plain-vector alias: __builtin_nontemporal_* rejects HIP_vector_type
typedef float f32x4 __attribute__((ext_vector_type(4)));

// ---- kernel 0: reset the 8 per-region descriptor counters (graph-safe) ----
__global__ void zero_rc(int* __restrict__ rc) {
    if (threadIdx.x < 8) rc[threadIdx.x] = 0;
}

// ---- kernel 1: scan ids, emit DENSE 64B group descriptors (v7 verbatim) ----
__global__ __launch_bounds__(256) void scan_kernel(
    const int* __restrict__ ids, int* __restrict__ rc, int* __restrict__ desc)
{
    __shared__ int toklist[MAXPER];
    __shared__ int cnt, basew;
    const int t = threadIdx.x;
    const int agent = blockIdx.x;
    if (t == 0) cnt = 0;
    __syncthreads();
    #pragma unroll
    for (int it = 0; it < NTOK / 1024; ++it) {          // 8 iters of int4
        int4 v = ((const int4*)ids)[t + 256 * it];
        int ib = 4 * (t + 256 * it);
        if ((v.x & (NUM_AGENTS - 1)) == agent) { int p = atomicAdd(&cnt, 1); if (p < MAXPER) toklist[p] = ib + 0; }
        if ((v.y & (NUM_AGENTS - 1)) == agent) { int p = atomicAdd(&cnt, 1); if (p < MAXPER) toklist[p] = ib + 1; }
        if ((v.z & (NUM_AGENTS - 1)) == agent) { int p = atomicAdd(&cnt, 1); if (p < MAXPER) toklist[p] = ib + 2; }
        if ((v.w & (NUM_AGENTS - 1)) == agent) { int p = atomicAdd(&cnt, 1); if (p < MAXPER) toklist[p] = ib + 3; }
    }
    __syncthreads();
    const int c = min(cnt, MAXPER);
    const int ng = (c + TBATCH - 1) / TBATCH;
    if (t == 0 && c > 0)
        basew = atomicAdd(&rc[agent & 7], ng);
    __syncthreads();
    if (t < ng) {
        int slot = basew + t;
        if (slot < REGCAP) {
            int* d = desc + ((size_t)(agent & 7) * REGCAP + slot) * 16;
            d[0] = agent;
            d[1] = min(TBATCH, c - t * TBATCH);
            #pragma unroll
            for (int m = 0; m < TBATCH; ++m)
                d[2 + m] = toklist[min(t * TBATCH + m, c - 1)];
        }
    }
}

// ---- kernel 2: ZERO-BARRIER compute. One wave = 2 tokens, end to end. -----
// Grid = 8 regions x REGCAP (v7's dense per-XCD dispatch). 4 waves per block,
// wave w owns tokens {2w, 2w+1}: stages its own 2 Hs rows (wave-private, LDS
// ops are wave-ordered -> NO __syncthreads in the whole kernel), sweeps all
// of U (coalesced 1KB/instr; 4x L2 reads/block, L2-absorbed), reduces inter
// IN REGISTERS (butterfly shfl), broadcasts inter quads by __shfl (replaces
// v7's LDS merge + 2 barriers), sweeps V, does LN stats by a 64-lane
// butterfly (replaces wred LDS + barrier). Hypothesis: v7's residual 23us
// block lifetime is barrier-quantized lockstep; independent waves let the CU
// scheduler hide each wave's latency separately.
//   inter[m] = h[m].U[a];  pert[m] = inter[m].V[a];
//   out[m] = LayerNorm(h[m] + alpha*pert[m]) * gamma + beta
__global__ __launch_bounds__(256) void div_inject_kernel(
    const float* __restrict__ hglob,
    const float* __restrict__ log_alpha,
    const float* __restrict__ gamma,
    const float* __restrict__ beta,
    const float* __restrict__ U,
    const float* __restrict__ V,
    const int* __restrict__ rc,
    const int* __restrict__ desc,
    float* __restrict__ out)
{
    __shared__ __align__(16) float Hs[TBATCH][HIDDEN];   // 32768 B, wave-private rows

    const int t = threadIdx.x;
    const int region = blockIdx.x & 7;
    const int slot = blockIdx.x >> 3;

    const int rcnt = min(rc[region], REGCAP);
    if (slot >= rcnt) return;

    const int* dsc = desc + ((size_t)region * REGCAP + slot) * 16;
    const int a  = dsc[0];
    const int nm = dsc[1];

    const int w = t >> 6, l = t & 63;
    const int m0 = 2 * w, m1 = 2 * w + 1;
    const int tk0 = dsc[2 + m0];          // padded by replication in scan
    const int tk1 = dsc[2 + m1];

    const float* Ua = U + (size_t)a * (HIDDEN * RANK);
    const float* Va = V + (size_t)a * (RANK * HIDDEN);

    const int cq = l * 4;          // column-quad base: cols cq + 256*k, k=0..3
    const int r4 = (l & 7) * 4;    // rank quad
    const int ks = l >> 3;         // k-slice 0..7

    const float alpha = fminf(__expf(log_alpha[0]), ALPHA_MAX);

    // ---- stage this wave's two h rows (wave-private; no barrier) ----
    #pragma unroll
    for (int k = 0; k < 4; ++k) {
        *(f32x4*)(&Hs[m0][cq + 256 * k]) =
            __builtin_nontemporal_load((const f32x4*)(hglob + (size_t)tk0 * HIDDEN + cq + 256 * k));
        *(f32x4*)(&Hs[m1][cq + 256 * k]) =
            __builtin_nontemporal_load((const f32x4*)(hglob + (size_t)tk1 * HIDDEN + cq + 256 * k));
    }

    // ---- phase B: inter[tok][r4..r4+3] partial over k-slices ----
    // per it: lanes cover hh=8it..8it+7 x all 32 ranks -> 1KB contiguous U load
    float4 a0 = make_float4(0.f, 0.f, 0.f, 0.f);
    float4 a1 = make_float4(0.f, 0.f, 0.f, 0.f);
    #pragma unroll 8
    for (int it = 0; it < 128; ++it) {
        const int hh = ks + 8 * it;
        float4 u = *(const float4*)(Ua + hh * RANK + r4);
        float h0 = Hs[m0][hh];            // 8-way LDS broadcast, conflict-free
        float h1 = Hs[m1][hh];
        a0.x += h0 * u.x; a0.y += h0 * u.y; a0.z += h0 * u.z; a0.w += h0 * u.w;
        a1.x += h1 * u.x; a1.y += h1 * u.y; a1.z += h1 * u.z; a1.w += h1 * u.w;
    }
    // butterfly over the 8 k-slices (lane bits 3..5): inter complete per lane
    #pragma unroll
    for (int off = 8; off <= 32; off <<= 1) {
        a0.x += __shfl_xor(a0.x, off, 64); a0.y += __shfl_xor(a0.y, off, 64);
        a0.z += __shfl_xor(a0.z, off, 64); a0.w += __shfl_xor(a0.w, off, 64);
        a1.x += __shfl_xor(a1.x, off, 64); a1.y += __shfl_xor(a1.y, off, 64);
        a1.z += __shfl_xor(a1.z, off, 64); a1.w += __shfl_xor(a1.w, off, 64);
    }

    // ---- phase C: pert[tok][cq+256k] = sum_r inter[tok][r] * V[r][..] ----
    // inter quad rb lives in lane rb (l&7==rb) -> register broadcast via shfl
    float4 p0[4], p1[4];
    #pragma unroll
    for (int k = 0; k < 4; ++k) {
        p0[k] = make_float4(0.f, 0.f, 0.f, 0.f);
        p1[k] = make_float4(0.f, 0.f, 0.f, 0.f);
    }
    #pragma unroll
    for (int rb = 0; rb < 8; ++rb) {
        float4 i0, i1;
        i0.x = __shfl(a0.x, rb, 64); i0.y = __shfl(a0.y, rb, 64);
        i0.z = __shfl(a0.z, rb, 64); i0.w = __shfl(a0.w, rb, 64);
        i1.x = __shfl(a1.x, rb, 64); i1.y = __shfl(a1.y, rb, 64);
        i1.z = __shfl(a1.z, rb, 64); i1.w = __shfl(a1.w, rb, 64);
        const float* Vr = Va + (size_t)(rb * 4) * HIDDEN + cq;
        #define PVSTEP(J, CM)                                                      \
        {                                                                          \
            _Pragma("unroll")                                                      \
            for (int k = 0; k < 4; ++k) {                                          \
                float4 v = *(const float4*)(Vr + (J) * HIDDEN + 256 * k);          \
                p0[k].x += i0.CM * v.x; p0[k].y += i0.CM * v.y;                    \
                p0[k].z += i0.CM * v.z; p0[k].w += i0.CM * v.w;                    \
                p1[k].x += i1.CM * v.x; p1[k].y += i1.CM * v.y;                    \
                p1[k].z += i1.CM * v.z; p1[k].w += i1.CM * v.w;                    \
            }                                                                      \
        }
        PVSTEP(0, x) PVSTEP(1, y) PVSTEP(2, z) PVSTEP(3, w)
        #undef PVSTEP
    }

    // ---- phase D: d = h + alpha*p in place; LN stats by 64-lane butterfly ----
    float s0 = 0.f, q0 = 0.f, s1 = 0.f, q1 = 0.f;
    #pragma unroll
    for (int k = 0; k < 4; ++k) {
        f32x4 h40 = *(const f32x4*)(&Hs[m0][cq + 256 * k]);
        f32x4 h41 = *(const f32x4*)(&Hs[m1][cq + 256 * k]);
        p0[k].x = h40.x + alpha * p0[k].x; p0[k].y = h40.y + alpha * p0[k].y;
        p0[k].z = h40.z + alpha * p0[k].z; p0[k].w = h40.w + alpha * p0[k].w;
        p1[k].x = h41.x + alpha * p1[k].x; p1[k].y = h41.y + alpha * p1[k].y;
        p1[k].z = h41.z + alpha * p1[k].z; p1[k].w = h41.w + alpha * p1[k].w;
        s0 += p0[k].x + p0[k].y + p0[k].z + p0[k].w;
        q0 += p0[k].x * p0[k].x + p0[k].y * p0[k].y + p0[k].z * p0[k].z + p0[k].w * p0[k].w;
        s1 += p1[k].x + p1[k].y + p1[k].z + p1[k].w;
        q1 += p1[k].x * p1[k].x + p1[k].y * p1[k].y + p1[k].z * p1[k].z + p1[k].w * p1[k].w;
    }
    #pragma unroll
    for (int off = 1; off <= 32; off <<= 1) {
        s0 += __shfl_xor(s0, off, 64); q0 += __shfl_xor(q0, off, 64);
        s1 += __shfl_xor(s1, off, 64); q1 += __shfl_xor(q1, off, 64);
    }
    const float inv = 1.0f / HIDDEN;
    const float mean0 = s0 * inv, rstd0 = rsqrtf(q0 * inv - mean0 * mean0 + LN_EPS);
    const float mean1 = s1 * inv, rstd1 = rsqrtf(q1 * inv - mean1 * mean1 + LN_EPS);

    #pragma unroll
    for (int k = 0; k < 4; ++k) {
        float4 gvk = *(const float4*)(gamma + cq + 256 * k);
        float4 bvk = *(const float4*)(beta + cq + 256 * k);
        if (m0 < nm) {                     // wave-uniform guard
            f32x4 o;
            o.x = (p0[k].x - mean0) * rstd0 * gvk.x + bvk.x;
            o.y = (p0[k].y - mean0) * rstd0 * gvk.y + bvk.y;
            o.z = (p0[k].z - mean0) * rstd0 * gvk.z + bvk.z;
            o.w = (p0[k].w - mean0) * rstd0 * gvk.w + bvk.w;
            __builtin_nontemporal_store(o, (f32x4*)(out + (size_t)tk0 * HIDDEN + cq + 256 * k));
        }
        if (m1 < nm) {
            f32x4 o;
            o.x = (p1[k].x - mean1) * rstd1 * gvk.x + bvk.x;
            o.y = (p1[k].y - mean1) * rstd1 * gvk.y + bvk.y;
            o.z = (p1[k].z - mean1) * rstd1 * gvk.z + bvk.z;
            o.w = (p1[k].w - mean1) * rstd1 * gvk.w + bvk.w;
            __builtin_nontemporal_store(o, (f32x4*)(out + (size_t)tk1 * HIDDEN + cq + 256 * k));
        }
    }
}

extern "C" void kernel_launch(void* const* d_in, const int* in_sizes, int n_in,
                              void* d_out, int out_size, void* d_ws, size_t ws_size,
                              hipStream_t stream) {
    const float* h     = (const float*)d_in[0];
    const float* la    = (const float*)d_in[1];
    const float* gamma = (const float*)d_in[2];
    const float* beta  = (const float*)d_in[3];
    const float* U     = (const float*)d_in[4];
    const float* V     = (const float*)d_in[5];
    const int* ids     = (const int*)d_in[6];
    float* out         = (float*)d_out;

    int* rc   = (int*)d_ws;                 // 8 counters (64 B reserved)
    int* desc = rc + 16;                    // 8 regions x REGCAP x 16 ints = 128 KB

    zero_rc<<<1, 64, 0, stream>>>(rc);
    scan_kernel<<<NUM_AGENTS, 256, 0, stream>>>(ids, rc, desc);
    div_inject_kernel<<<8 * REGCAP, 256, 0, stream>>>(
        h, la, gamma, beta, U, V, rc, desc, out);
}

// Round 14
// 167.129 us; speedup vs baseline: 1.2547x; 1.2547x over previous
//
#include <hip/hip_runtime.h>
#include <math.h>

#define NUM_AGENTS 256
#define HIDDEN 1024
#define RANK 32
#define NTOK 8192
#define TBATCH 8          // tokens per compute block
#define MAXPER 128        // per-agent token cap (Binomial mean 32; 128 = +17 sigma)
#define REGCAP 256        // descriptor slots per XCD region
#define ALPHA_MAX 5.0f
#define LN_EPS 1e-5f

// plain-vector alias: __builtin_nontemporal_* rejects HIP_vector_type
typedef float f32x4 __attribute__((ext_vector_type(4)));

// ---- kernel 0: reset the 8 per-region descriptor counters (graph-safe) ----
__global__ void zero_rc(int* __restrict__ rc) {
    if (threadIdx.x < 8) rc[threadIdx.x] = 0;
}

// ---- kernel 1: scan ids, emit DENSE 64B group descriptors ------------------
// Grid 256 (one block per agent). Collect the agent's tokens in LDS, then
// reserve contiguous slots in region (agent & 7) via ONE global atomic and
// write descriptors {agent, nm, tk[0..7]} (padded by replication). Same-agent
// groups land in one region -> one XCD -> U/V L2 reuse; regions balanced.
__global__ __launch_bounds__(256) void scan_kernel(
    const int* __restrict__ ids, int* __restrict__ rc, int* __restrict__ desc)
{
    __shared__ int toklist[MAXPER];
    __shared__ int cnt, basew;
    const int t = threadIdx.x;
    const int agent = blockIdx.x;
    if (t == 0) cnt = 0;
    __syncthreads();
    #pragma unroll
    for (int it = 0; it < NTOK / 1024; ++it) {          // 8 iters of int4
        int4 v = ((const int4*)ids)[t + 256 * it];
        int ib = 4 * (t + 256 * it);
        if ((v.x & (NUM_AGENTS - 1)) == agent) { int p = atomicAdd(&cnt, 1); if (p < MAXPER) toklist[p] = ib + 0; }
        if ((v.y & (NUM_AGENTS - 1)) == agent) { int p = atomicAdd(&cnt, 1); if (p < MAXPER) toklist[p] = ib + 1; }
        if ((v.z & (NUM_AGENTS - 1)) == agent) { int p = atomicAdd(&cnt, 1); if (p < MAXPER) toklist[p] = ib + 2; }
        if ((v.w & (NUM_AGENTS - 1)) == agent) { int p = atomicAdd(&cnt, 1); if (p < MAXPER) toklist[p] = ib + 3; }
    }
    __syncthreads();
    const int c = min(cnt, MAXPER);
    const int ng = (c + TBATCH - 1) / TBATCH;
    if (t == 0 && c > 0)
        basew = atomicAdd(&rc[agent & 7], ng);
    __syncthreads();
    if (t < ng) {
        int slot = basew + t;
        if (slot < REGCAP) {
            int* d = desc + ((size_t)(agent & 7) * REGCAP + slot) * 16;
            d[0] = agent;
            d[1] = min(TBATCH, c - t * TBATCH);
            #pragma unroll
            for (int m = 0; m < TBATCH; ++m)
                d[2 + m] = toklist[min(t * TBATCH + m, c - 1)];
        }
    }
}

// ---- kernel 2: one block = one descriptor (group of <=8 tokens) ------------
// Grid = 8 regions x REGCAP, block -> (region = bid & 7, slot = bid >> 3).
// Round-robin XCD assignment puts region x on XCD x -> same-agent groups
// share an L2. Prologue is ONE uniform 64B descriptor load; then h rows,
// U batch 0 and alpha issue concurrently.
//   inter[m] = h[m].U[a];  pert[m] = inter[m].V[a];
//   out[m] = LayerNorm(h[m] + alpha*pert[m]) * gamma + beta
// LDS = exactly 32768 B (red/inter/wred aliased onto Hs[0]; row-0 fragment
// kept in h0v regs; transitions barrier-separated). 68 VGPR — the register-
// stable formulation (any added loop/unroll state spills or halves occupancy:
// measured R3/R8/R9). Best measured: 52 us kernel / 166.8 us bench (R7),
// reproduced at 52-55 us in R12.
__global__ __launch_bounds__(256) void div_inject_kernel(
    const float* __restrict__ hglob,
    const float* __restrict__ log_alpha,
    const float* __restrict__ gamma,
    const float* __restrict__ beta,
    const float* __restrict__ U,
    const float* __restrict__ V,
    const int* __restrict__ rc,
    const int* __restrict__ desc,
    float* __restrict__ out)
{
    __shared__ __align__(16) float Hs[TBATCH][HIDDEN];   // 32768 B — everything
    // Alias plan inside Hs[0][0..1023]:
    //   red0[w*256 + m*32 + r] : phase-2 per-wave partials
    //   inter[m*32 + r]        : merged intermediate (red0[0..255])
    //   wred[w*16 + {0|8} + m] : LN partials (red0[256..319], disjoint)
    float* red0  = &Hs[0][0];
    float* inter = red0;
    float* wred  = red0 + 256;

    const int t = threadIdx.x;
    const int region = blockIdx.x & 7;
    const int slot = blockIdx.x >> 3;

    const int rcnt = min(rc[region], REGCAP);
    if (slot >= rcnt) return;

    const int* dsc = desc + ((size_t)region * REGCAP + slot) * 16;
    const int a  = dsc[0];
    const int nm = dsc[1];
    int tk[TBATCH];
    #pragma unroll
    for (int m = 0; m < TBATCH; ++m) tk[m] = dsc[2 + m];

    const float* Ua = U + (size_t)a * (HIDDEN * RANK);
    const float* Va = V + (size_t)a * (RANK * HIDDEN);

    const int r4 = (t & 7) * 4;   // rank quad: 0,4,...,28
    const int ks = t >> 3;        // k-slice 0..31
    const int c  = t * 4;         // this thread's 4 output columns
    const int wave = t >> 6, lane = t & 63;

    // ---- issue U batch 0 immediately ----
    float4 ub[2][4];
    #pragma unroll
    for (int j = 0; j < 4; ++j)
        ub[0][j] = *(const float4*)(Ua + (ks + 32 * j) * RANK + r4);

    const float alpha = fminf(__expf(log_alpha[0]), ALPHA_MAX);

    // ---- stage h rows; keep row-0 fragment in regs (Hs[0] reused as red) ----
    f32x4 h0v;
    {
        f32x4 hv[TBATCH];
        #pragma unroll
        for (int m = 0; m < TBATCH; ++m)
            hv[m] = __builtin_nontemporal_load((const f32x4*)(hglob + (size_t)tk[m] * HIDDEN + c));
        h0v = hv[0];
        #pragma unroll
        for (int m = 0; m < TBATCH; ++m)
            *(f32x4*)(&Hs[m][c]) = hv[m];
    }
    __syncthreads();                       // [A] Hs ready

    // ---- phase 2: inter[m][r] = sum_hh Hs[m][hh] * U[hh][r] ----
    // depth-4 double-buffered U pipeline
    float4 acc[TBATCH];
    #pragma unroll
    for (int m = 0; m < TBATCH; ++m) acc[m] = make_float4(0.f, 0.f, 0.f, 0.f);
    #pragma unroll
    for (int jb = 0; jb < 8; ++jb) {
        const int cur = jb & 1;
        if (jb < 7) {
            #pragma unroll
            for (int j = 0; j < 4; ++j)
                ub[cur ^ 1][j] = *(const float4*)(Ua + (ks + 32 * (4 * (jb + 1) + j)) * RANK + r4);
        }
        #pragma unroll
        for (int j = 0; j < 4; ++j) {
            const int hh = ks + 32 * (4 * jb + j);
            float4 u = ub[cur][j];
            #pragma unroll
            for (int m = 0; m < TBATCH; ++m) {
                float h0 = Hs[m][hh];
                acc[m].x += h0 * u.x;
                acc[m].y += h0 * u.y;
                acc[m].z += h0 * u.z;
                acc[m].w += h0 * u.w;
            }
        }
    }
    // reduce over the 8 k-slices within each wave (lane bits 3..5)
    #pragma unroll
    for (int off = 8; off <= 32; off <<= 1) {
        #pragma unroll
        for (int m = 0; m < TBATCH; ++m) {
            acc[m].x += __shfl_xor(acc[m].x, off, 64);
            acc[m].y += __shfl_xor(acc[m].y, off, 64);
            acc[m].z += __shfl_xor(acc[m].z, off, 64);
            acc[m].w += __shfl_xor(acc[m].w, off, 64);
        }
    }
    __syncthreads();                       // [B] all Hs[0] reads done -> reusable
    if (lane < 8) {
        #pragma unroll
        for (int m = 0; m < TBATCH; ++m)
            *(float4*)(&red0[wave * 256 + m * 32 + r4]) = acc[m];
    }

    // prefetch V batch 0 before the merge barrier
    float4 vb[2][4];
    #pragma unroll
    for (int j = 0; j < 4; ++j)
        vb[0][j] = *(const float4*)(Va + j * HIDDEN + c);

    __syncthreads();                       // [C] red written
    {
        int m = t >> 5, rr = t & 31;       // thread-exclusive RMW merge
        inter[m * 32 + rr] = red0[m * 32 + rr] + red0[256 + m * 32 + rr]
                           + red0[512 + m * 32 + rr] + red0[768 + m * 32 + rr];
    }
    __syncthreads();                       // [D] inter ready

    // ---- phase 3: p[m][c..c+3] = sum_r inter[m][r] * V[r][c..c+3] ----
    float4 p[TBATCH];
    #pragma unroll
    for (int m = 0; m < TBATCH; ++m) p[m] = make_float4(0.f, 0.f, 0.f, 0.f);
    #pragma unroll
    for (int rb = 0; rb < 8; ++rb) {
        const int cur = rb & 1;
        if (rb < 7) {
            #pragma unroll
            for (int j = 0; j < 4; ++j)
                vb[cur ^ 1][j] = *(const float4*)(Va + (4 * (rb + 1) + j) * HIDDEN + c);
        }
        #pragma unroll
        for (int j = 0; j < 4; ++j) {
            const int r = 4 * rb + j;
            float4 v = vb[cur][j];
            #pragma unroll
            for (int m = 0; m < TBATCH; ++m) {
                float ir = inter[m * 32 + r];   // uniform LDS broadcast
                p[m].x += ir * v.x;
                p[m].y += ir * v.y;
                p[m].z += ir * v.z;
                p[m].w += ir * v.w;
            }
        }
    }

    // ---- d = h + alpha*p IN PLACE; LayerNorm stats (m=0 h from regs) ----
    float s[TBATCH], q[TBATCH];
    #pragma unroll
    for (int m = 0; m < TBATCH; ++m) {
        f32x4 h4 = (m == 0) ? h0v : *(const f32x4*)(&Hs[m][c]);
        p[m].x = h4.x + alpha * p[m].x;
        p[m].y = h4.y + alpha * p[m].y;
        p[m].z = h4.z + alpha * p[m].z;
        p[m].w = h4.w + alpha * p[m].w;
        s[m] = p[m].x + p[m].y + p[m].z + p[m].w;
        q[m] = p[m].x * p[m].x + p[m].y * p[m].y + p[m].z * p[m].z + p[m].w * p[m].w;
    }
    #pragma unroll
    for (int off = 32; off > 0; off >>= 1) {
        #pragma unroll
        for (int m = 0; m < TBATCH; ++m) {
            s[m] += __shfl_xor(s[m], off, 64);
            q[m] += __shfl_xor(q[m], off, 64);
        }
    }
    if (lane == 0) {
        #pragma unroll
        for (int m = 0; m < TBATCH; ++m) {     // static indices only
            wred[wave * 16 + m] = s[m];
            wred[wave * 16 + 8 + m] = q[m];
        }
    }
    __syncthreads();                       // [E] stats partials ready

    // stats computed redundantly by every thread (LDS broadcasts)
    const float4 gv = *(const float4*)(gamma + c);
    const float4 bv = *(const float4*)(beta + c);
    #pragma unroll
    for (int m = 0; m < TBATCH; ++m) {
        if (m < nm) {                        // nm block-uniform
            float S = wred[m] + wred[16 + m] + wred[32 + m] + wred[48 + m];
            float Q = wred[8 + m] + wred[24 + m] + wred[40 + m] + wred[56 + m];
            float mean = S * (1.0f / HIDDEN);
            float rstd = rsqrtf(Q * (1.0f / HIDDEN) - mean * mean + LN_EPS);
            f32x4 o;
            o.x = (p[m].x - mean) * rstd * gv.x + bv.x;
            o.y = (p[m].y - mean) * rstd * gv.y + bv.y;
            o.z = (p[m].z - mean) * rstd * gv.z + bv.z;
            o.w = (p[m].w - mean) * rstd * gv.w + bv.w;
            __builtin_nontemporal_store(o, (f32x4*)(out + (size_t)tk[m] * HIDDEN + c));
        }
    }
}

extern "C" void kernel_launch(void* const* d_in, const int* in_sizes, int n_in,
                              void* d_out, int out_size, void* d_ws, size_t ws_size,
                              hipStream_t stream) {
    const float* h     = (const float*)d_in[0];
    const float* la    = (const float*)d_in[1];
    const float* gamma = (const float*)d_in[2];
    const float* beta  = (const float*)d_in[3];
    const float* U     = (const float*)d_in[4];
    const float* V     = (const float*)d_in[5];
    const int* ids     = (const int*)d_in[6];
    float* out         = (float*)d_out;

    int* rc   = (int*)d_ws;                 // 8 counters (64 B reserved)
    int* desc = rc + 16;                    // 8 regions x REGCAP x 16 ints = 128 KB

    zero_rc<<<1, 64, 0, stream>>>(rc);
    scan_kernel<<<NUM_AGENTS, 256, 0, stream>>>(ids, rc, desc);
    div_inject_kernel<<<8 * REGCAP, 256, 0, stream>>>(
        h, la, gamma, beta, U, V, rc, desc, out);
}